// Round 4
// baseline (261.138 us; speedup 1.0000x reference)
//
#include <hip/hip_runtime.h>
#include <cstdint>
#include <cstddef>

typedef unsigned short u16;
typedef unsigned int u32;
typedef __attribute__((ext_vector_type(4))) float f32x4;
typedef __attribute__((ext_vector_type(8))) __bf16 bf16x8;
typedef __attribute__((ext_vector_type(8))) u16 u16x8;
typedef __attribute__((ext_vector_type(4))) u16 u16x4;

__device__ __forceinline__ u16 f2bf(float x) {
  u32 u = __builtin_bit_cast(u32, x);
  u += 0x7fffu + ((u >> 16) & 1u);
  return (u16)(u >> 16);
}
__device__ __forceinline__ float bf2f(u16 b) {
  return __builtin_bit_cast(float, (u32)b << 16);
}
__device__ __forceinline__ bf16x8 ldfrag(const u16* p) {
  return __builtin_bit_cast(bf16x8, *(const u16x8*)p);
}
__device__ __forceinline__ void gload_lds16(const void* g, void* l) {
  auto gp = (const __attribute__((address_space(1))) u32*)g;
  auto lp = (__attribute__((address_space(3))) u32*)l;
  __builtin_amdgcn_global_load_lds(gp, lp, 16, 0, 0);
}
#define MFMA16(a, b, c) __builtin_amdgcn_mfma_f32_16x16x32_bf16(a, b, c, 0, 0, 0)

// ---------------- elementwise converts ----------------

__global__ void cvt_kernel(const float* __restrict__ in, u16* __restrict__ out, int n) {
  int i = (blockIdx.x * blockDim.x + threadIdx.x) * 4;
  if (i >= n) return;
  f32x4 v = *(const f32x4*)(in + i);
  u16x4 r = { f2bf(v[0]), f2bf(v[1]), f2bf(v[2]), f2bf(v[3]) };
  *(u16x4*)(out + i) = r;
}

// out[C][R] = bf16(in[R][C]^T), tiled transpose via LDS
__global__ void tcvt_kernel(const float* __restrict__ in, u16* __restrict__ out, int R, int C) {
  __shared__ float tile[32][33];
  int bx = blockIdx.x * 32, by = blockIdx.y * 32;
  int tx = threadIdx.x, ty = threadIdx.y;
#pragma unroll
  for (int i = 0; i < 32; i += 8)
    tile[ty + i][tx] = in[(size_t)(by + ty + i) * C + bx + tx];
  __syncthreads();
#pragma unroll
  for (int i = 0; i < 32; i += 8)
    out[(size_t)(bx + ty + i) * R + by + tx] = f2bf(tile[tx][ty + i]);
}

// Aq = gq*P, Ak = gk*P, Av = gv*Pv ; P/Pv live interleaved in Pcat[4096][1024]
__global__ void gate_kernel(const float* __restrict__ gq, const float* __restrict__ gk,
                            const float* __restrict__ gv, const u16* __restrict__ Pcat,
                            u16* __restrict__ Aq, u16* __restrict__ Ak, u16* __restrict__ Av,
                            int n) {
  int i = (blockIdx.x * blockDim.x + threadIdx.x) * 4;
  if (i >= n) return;
  int s = i >> 9;
  int r = i & 511;
  u16x4 pq = *(const u16x4*)(Pcat + (size_t)s * 1024 + r);
  u16x4 pv = *(const u16x4*)(Pcat + (size_t)s * 1024 + 512 + r);
  f32x4 q = *(const f32x4*)(gq + i);
  f32x4 k = *(const f32x4*)(gk + i);
  f32x4 v = *(const f32x4*)(gv + i);
  u16x4 aq, ak, av;
#pragma unroll
  for (int j = 0; j < 4; ++j) {
    float pf = bf2f(pq[j]);
    float vf = bf2f(pv[j]);
    aq[j] = f2bf(q[j] * pf);
    ak[j] = f2bf(k[j] * pf);
    av[j] = f2bf(v[j] * vf);
  }
  *(u16x4*)(Aq + i) = aq;
  *(u16x4*)(Ak + i) = ak;
  *(u16x4*)(Av + i) = av;
}

// ---------------- generic C = A * Bt^T GEMM ----------------
// A[M][K] bf16 row-major, Bt[N][K] bf16 row-major, C[M][N] (bf16 or f32*scale)
template <bool F32OUT>
__global__ void gemm_bt(const u16* __restrict__ A, const u16* __restrict__ Bt,
                        void* __restrict__ Cp, int M, int N, int K, float scale) {
  __shared__ u16 Al[128 * 32];
  __shared__ u16 Bl[128 * 32];
  const int tid = threadIdx.x;
  const int lane = tid & 63;
  const int w = tid >> 6;
  const int wr = (w >> 1) * 64;
  const int wc = (w & 1) * 64;
  const size_t bm = (size_t)blockIdx.y * 128;
  const size_t bn = (size_t)blockIdx.x * 128;

  f32x4 acc[4][4] = {};

  const int srow = lane >> 2;
  const int sch = lane & 3;
  const int kc = lane >> 4;
  const int rl = lane & 15;

  for (int kt = 0; kt < K; kt += 32) {
#pragma unroll
    for (int half = 0; half < 2; ++half) {
      int rb = half * 64 + w * 16;
      int row = rb + srow;
      int ch = sch ^ ((row >> 1) & 3);
      gload_lds16(A + (bm + row) * (size_t)K + kt + ch * 8, &Al[rb * 32]);
    }
#pragma unroll
    for (int half = 0; half < 2; ++half) {
      int rb = half * 64 + w * 16;
      int row = rb + srow;
      int ch = sch ^ ((row >> 1) & 3);
      gload_lds16(Bt + (bn + row) * (size_t)K + kt + ch * 8, &Bl[rb * 32]);
    }
    asm volatile("s_waitcnt vmcnt(0)" ::: "memory");
    __syncthreads();

    bf16x8 af[4], bfr[4];
#pragma unroll
    for (int m = 0; m < 4; ++m) {
      int row = wr + m * 16 + rl;
      af[m] = ldfrag(&Al[row * 32 + (kc ^ ((row >> 1) & 3)) * 8]);
    }
#pragma unroll
    for (int n = 0; n < 4; ++n) {
      int row = wc + n * 16 + rl;
      bfr[n] = ldfrag(&Bl[row * 32 + (kc ^ ((row >> 1) & 3)) * 8]);
    }
#pragma unroll
    for (int m = 0; m < 4; ++m)
#pragma unroll
      for (int n = 0; n < 4; ++n)
        acc[m][n] = MFMA16(af[m], bfr[n], acc[m][n]);
    __syncthreads();
  }

  const int r0 = (lane >> 4) * 4;
#pragma unroll
  for (int m = 0; m < 4; ++m) {
    size_t grow = bm + wr + m * 16 + r0;
#pragma unroll
    for (int n = 0; n < 4; ++n) {
      size_t gcol = bn + wc + n * 16 + rl;
#pragma unroll
      for (int r = 0; r < 4; ++r) {
        float v = acc[m][n][r] * scale;
        if constexpr (F32OUT)
          ((float*)Cp)[(grow + r) * (size_t)N + gcol] = v;
        else
          ((u16*)Cp)[(grow + r) * (size_t)N + gcol] = f2bf(v);
      }
    }
  }
}

// ---------------- flash attention (causal, 16 heads, d_head=128) ----------------
// grid: x = bh (32) -> blocks sharing a head's K/V land on one XCD (T1);
//       y = pair index (16): q-tiles (31-pi, pi) of 64 rows -> uniform 33 KV-iters.
// 4 waves x 16 q-rows. LDS 48KB (Kl dbuf 32K + Vl single 16K; P aliased into
// Kl[cur]) -> 3 blocks/CU. V staged per-tile w/ counted vmcnt(4) (T4);
// K prefetched across the end barrier; raw mid s_barrier guards P alias.
__global__ __launch_bounds__(256, 3) void attn_kernel(const u16* __restrict__ Q,
                                                      const u16* __restrict__ Kg,
                                                      const u16* __restrict__ Vt,
                                                      u16* __restrict__ AO) {
  __shared__ u16 Kl[2][64 * 128];  // 32 KB; P (4KB) aliases into Kl[cur]
  __shared__ u16 Vl[128 * 64];     // 16 KB

  const int tid = threadIdx.x;
  const int lane = tid & 63;
  const int w = tid >> 6;
  const int bh = blockIdx.x;
  const int pi = blockIdx.y;  // 0..15
  const int b = bh >> 4;
  const int h = bh & 15;

  const int rl = lane & 15;
  const int g4 = lane >> 4;

  const float SC = 0.1275255128608411f;  // 1/sqrt(128) * log2(e)
  const float THR = 10.0f;               // defer-rescale threshold (log2 units)

  bf16x8 ones;
  {
    u16x8 ou;
#pragma unroll
    for (int j = 0; j < 8; ++j) ou[j] = 0x3F80;  // bf16 1.0
    ones = __builtin_bit_cast(bf16x8, ou);
  }

  auto stageK = [&](int buf, int t0) {
    int roff = lane >> 4;
    int cch = lane & 15;
#pragma unroll
    for (int i = 0; i < 4; ++i) {
      int rb = w * 16 + i * 4;
      int row = rb + roff;
      int ch = cch ^ (row & 7);
      gload_lds16(Kg + ((size_t)b * 2048 + t0 + row) * 2048 + h * 128 + ch * 8,
                  &Kl[buf][rb * 128]);
    }
  };
  auto stageV = [&](int t0) {
    int roff = lane >> 3;
    int cch = lane & 7;
#pragma unroll
    for (int i = 0; i < 4; ++i) {
      int rb = w * 32 + i * 8;
      int row = rb + roff;
      int ch = cch ^ (row & 7);
      gload_lds16(Vt + (size_t)(h * 128 + row) * 4096 + (size_t)b * 2048 + t0 + ch * 8,
                  &Vl[rb * 64]);
    }
  };

  const int qbs[2] = {31 - pi, pi};

  stageK(0, 0);
  __syncthreads();
  int cur = 0;

#pragma unroll 1
  for (int ph = 0; ph < 2; ++ph) {
    const int qb = qbs[ph];
    const int ntiles = qb + 1;
    const int qbase = qb * 64 + w * 16;  // wave's first q row (within b)
    const size_t qrow0 = (size_t)b * 2048 + (size_t)qb * 64;

    bf16x8 qf[4];
    {
      const u16* qp = Q + (qrow0 + w * 16 + rl) * 2048 + h * 128 + g4 * 8;
#pragma unroll
      for (int ks = 0; ks < 4; ++ks) qf[ks] = ldfrag(qp + ks * 32);
    }

    float m_r[4], l_r[4];
#pragma unroll
    for (int r = 0; r < 4; ++r) { m_r[r] = -3.0e38f; l_r[r] = 0.f; }
    f32x4 oacc[8] = {};

#pragma unroll 1
    for (int t = 0; t < ntiles; ++t) {
      const int t0 = t * 64;
      stageV(t0);  // V for THIS tile (issued first; drained by vmcnt(4) below)
      const bool pref = (t + 1 < ntiles) || (ph == 0);
      if (pref) stageK(cur ^ 1, (t + 1 < ntiles) ? (t + 1) * 64 : 0);

      // ---- QK^T ----
      float p[4][4];
      float pmax[4] = {-3.0e38f, -3.0e38f, -3.0e38f, -3.0e38f};
      __builtin_amdgcn_s_setprio(1);
#pragma unroll
      for (int nf = 0; nf < 4; ++nf) {
        f32x4 c = {};
        int trow = nf * 16 + rl;
#pragma unroll
        for (int ks = 0; ks < 4; ++ks) {
          bf16x8 kf = ldfrag(&Kl[cur][trow * 128 + ((ks * 4 + g4) ^ (trow & 7)) * 8]);
          c = MFMA16(qf[ks], kf, c);
        }
        if (t == qb) {  // diagonal tile: causal mask
          int tc = t0 + nf * 16 + rl;
          int fragq = qbase + g4 * 4;  // + r
#pragma unroll
          for (int r = 0; r < 4; ++r)
            p[nf][r] = (tc <= fragq + r) ? c[r] * SC : -3.0e38f;
        } else {
#pragma unroll
          for (int r = 0; r < 4; ++r) p[nf][r] = c[r] * SC;
        }
#pragma unroll
        for (int r = 0; r < 4; ++r) pmax[r] = fmaxf(pmax[r], p[nf][r]);
      }
      __builtin_amdgcn_s_setprio(0);

      // row-max across the 16 t-columns held by rl lanes (register-only)
#pragma unroll
      for (int off = 1; off < 16; off <<= 1)
#pragma unroll
        for (int r = 0; r < 4; ++r)
          pmax[r] = fmaxf(pmax[r], __shfl_xor(pmax[r], off, 16));

      // T13 defer-rescale
      float mg = -3.0e38f;
#pragma unroll
      for (int r = 0; r < 4; ++r) mg = fmaxf(mg, pmax[r] - m_r[r]);
      if (__any(mg > THR)) {
#pragma unroll
        for (int r = 0; r < 4; ++r) {
          float mn = fmaxf(m_r[r], pmax[r]);
          float alpha = exp2f(m_r[r] - mn);
          m_r[r] = mn;
          l_r[r] *= alpha;
#pragma unroll
          for (int nf = 0; nf < 8; ++nf) oacc[nf][r] *= alpha;
        }
      }

      // exp (register-only, before barrier to hide barrier wait)
      float e[4][4];
#pragma unroll
      for (int nf = 0; nf < 4; ++nf)
#pragma unroll
        for (int r = 0; r < 4; ++r) e[nf][r] = exp2f(p[nf][r] - m_r[r]);

      // Drain own V loads (K prefetch stays in flight), then join waves:
      // after this barrier all QK reads of Kl[cur] are done (register-consumed)
      // and all waves' V staging is complete.
      if (pref) asm volatile("s_waitcnt vmcnt(4)\n\ts_barrier" ::: "memory");
      else      asm volatile("s_waitcnt vmcnt(0)\n\ts_barrier" ::: "memory");

      // P -> LDS (bf16, swizzled), aliased into Kl[cur] (dead after QK^T)
      u16* pl = &Kl[cur][w * 1024];
#pragma unroll
      for (int nf = 0; nf < 4; ++nf) {
        int tt = nf * 16 + rl;
#pragma unroll
        for (int r = 0; r < 4; ++r) {
          int q = g4 * 4 + r;
          pl[q * 64 + ((tt >> 3) ^ (q & 7)) * 8 + (tt & 7)] = f2bf(e[nf][r]);
        }
      }

      // ---- PV (+ rsum via MFMA with ones) ----
      __builtin_amdgcn_s_setprio(1);
      f32x4 rs = {};
#pragma unroll
      for (int ks = 0; ks < 2; ++ks) {
        bf16x8 pa = ldfrag(&pl[rl * 64 + ((ks * 4 + g4) ^ (rl & 7)) * 8]);
#pragma unroll
        for (int nf = 0; nf < 8; ++nf) {
          int drow = nf * 16 + rl;
          bf16x8 vf = ldfrag(&Vl[drow * 64 + ((ks * 4 + g4) ^ (drow & 7)) * 8]);
          oacc[nf] = MFMA16(pa, vf, oacc[nf]);
        }
        rs = MFMA16(pa, ones, rs);
      }
      __builtin_amdgcn_s_setprio(0);
#pragma unroll
      for (int r = 0; r < 4; ++r) l_r[r] += rs[r];

      __syncthreads();  // all waves done with Vl/pl; drains K prefetch
      cur ^= 1;
    }

    // epilogue for this q-tile
#pragma unroll
    for (int nf = 0; nf < 8; ++nf) {
      size_t dc = (size_t)h * 128 + nf * 16 + rl;
#pragma unroll
      for (int r = 0; r < 4; ++r) {
        float v = oacc[nf][r] / l_r[r];
        AO[(qrow0 + w * 16 + g4 * 4 + r) * 2048 + dc] = f2bf(v);
      }
    }
  }
}

// ---------------- launch ----------------

extern "C" void kernel_launch(void* const* d_in, const int* in_sizes, int n_in,
                              void* d_out, int out_size, void* d_ws, size_t ws_size,
                              hipStream_t stream) {
  const float* x = (const float*)d_in[0];
  const float* gQ = (const float*)d_in[1];
  const float* gK = (const float*)d_in[2];
  const float* gV = (const float*)d_in[3];
  const float* qkr = (const float*)d_in[4];
  const float* qkw = (const float*)d_in[5];
  const float* vr = (const float*)d_in[6];
  const float* vw = (const float*)d_in[7];
  const float* wo = (const float*)d_in[8];
  float* out = (float*)d_out;

  u16* p = (u16*)d_ws;
  u16* x_bf = p;   p += 8388608;   // [4096][2048]; later reused as Vt [2048][4096]
  u16* qkr_b = p;  p += 1048576;   // [512][2048]  \ adjacent -> Bt_cat [1024][2048]
  u16* vr_b = p;   p += 1048576;   // [512][2048]  /
  u16* qkwT = p;   p += 1048576;   // [2048][512]
  u16* vwT = p;    p += 1048576;   // [2048][512]
  u16* woT = p;    p += 4194304;   // [2048][2048]
  u16* Pcat = p;   p += 4194304;   // [4096][1024] (P | Pv)
  u16* Aq = p;     p += 2097152;   // [4096][512]  \ adjacent -> A_cat [8192][512]
  u16* Ak = p;     p += 2097152;   // [4096][512]  /
  u16* Av = p;     p += 2097152;   // [4096][512]
  u16* Qb = p;     p += 8388608;   // [4096][2048] \ adjacent -> C_cat [8192][2048]
  u16* Kb = p;     p += 8388608;   // [4096][2048] /
  u16* Vt = x_bf;                  // alias: x_bf dead after Pcat GEMM
  u16* AO = Qb;                    // alias: block writes exactly the Q region it read

  cvt_kernel<<<8192, 256, 0, stream>>>(x, x_bf, 8388608);
  cvt_kernel<<<1024, 256, 0, stream>>>(qkr, qkr_b, 1048576);
  cvt_kernel<<<1024, 256, 0, stream>>>(vr, vr_b, 1048576);
  tcvt_kernel<<<dim3(64, 16), dim3(32, 8), 0, stream>>>(qkw, qkwT, 512, 2048);
  tcvt_kernel<<<dim3(64, 16), dim3(32, 8), 0, stream>>>(vw, vwT, 512, 2048);
  tcvt_kernel<<<dim3(64, 64), dim3(32, 8), 0, stream>>>(wo, woT, 2048, 2048);

  // Pcat = x_bf * [qk_read;v_read]^T   (M=4096, N=1024, K=2048)
  gemm_bt<false><<<dim3(8, 32), 256, 0, stream>>>(x_bf, qkr_b, Pcat, 4096, 1024, 2048, 1.f);

  gate_kernel<<<2048, 256, 0, stream>>>(gQ, gK, gV, Pcat, Aq, Ak, Av, 2097152);

  // [Q;K] = [Aq;Ak] * qk_write   (M=8192, N=2048, K=512)
  gemm_bt<false><<<dim3(16, 64), 256, 0, stream>>>(Aq, qkwT, Qb, 8192, 2048, 512, 1.f);

  // Vt = vwT * Av^T   (M=2048, N=4096, K=512)
  gemm_bt<false><<<dim3(32, 16), 256, 0, stream>>>(vwT, Av, Vt, 2048, 4096, 512, 1.f);

  // attention -> AO (bf16, [4096][2048])
  attn_kernel<<<dim3(32, 16), 256, 0, stream>>>(Qb, Kb, Vt, AO);

  // out = AO * W_O * 1/keep^2   (f32 out)
  gemm_bt<true><<<dim3(16, 32), 256, 0, stream>>>(AO, woT, out, 4096, 2048, 2048,
                                                  1.2345679012345678f);
}

// Round 5
// 247.631 us; speedup vs baseline: 1.0545x; 1.0545x over previous
//
#include <hip/hip_runtime.h>
#include <cstdint>
#include <cstddef>

typedef unsigned short u16;
typedef unsigned int u32;
typedef __attribute__((ext_vector_type(4))) float f32x4;
typedef __attribute__((ext_vector_type(8))) __bf16 bf16x8;
typedef __attribute__((ext_vector_type(8))) u16 u16x8;
typedef __attribute__((ext_vector_type(4))) u16 u16x4;

__device__ __forceinline__ u16 f2bf(float x) {
  u32 u = __builtin_bit_cast(u32, x);
  u += 0x7fffu + ((u >> 16) & 1u);
  return (u16)(u >> 16);
}
__device__ __forceinline__ u16 f2bf_trunc(float x) {
  return (u16)(__builtin_bit_cast(u32, x) >> 16);
}
__device__ __forceinline__ float bf2f(u16 b) {
  return __builtin_bit_cast(float, (u32)b << 16);
}
__device__ __forceinline__ bf16x8 ldfrag(const u16* p) {
  return __builtin_bit_cast(bf16x8, *(const u16x8*)p);
}
__device__ __forceinline__ void gload_lds16(const void* g, void* l) {
  auto gp = (const __attribute__((address_space(1))) u32*)g;
  auto lp = (__attribute__((address_space(3))) u32*)l;
  __builtin_amdgcn_global_load_lds(gp, lp, 16, 0, 0);
}
#define MFMA16(a, b, c) __builtin_amdgcn_mfma_f32_16x16x32_bf16(a, b, c, 0, 0, 0)

// ---------------- elementwise converts ----------------

__global__ void cvt_kernel(const float* __restrict__ in, u16* __restrict__ out, int n) {
  int i = (blockIdx.x * blockDim.x + threadIdx.x) * 4;
  if (i >= n) return;
  f32x4 v = *(const f32x4*)(in + i);
  u16x4 r = { f2bf(v[0]), f2bf(v[1]), f2bf(v[2]), f2bf(v[3]) };
  *(u16x4*)(out + i) = r;
}

// out[C][R] = bf16(in[R][C]^T), tiled transpose via LDS
__global__ void tcvt_kernel(const float* __restrict__ in, u16* __restrict__ out, int R, int C) {
  __shared__ float tile[32][33];
  int bx = blockIdx.x * 32, by = blockIdx.y * 32;
  int tx = threadIdx.x, ty = threadIdx.y;
#pragma unroll
  for (int i = 0; i < 32; i += 8)
    tile[ty + i][tx] = in[(size_t)(by + ty + i) * C + bx + tx];
  __syncthreads();
#pragma unroll
  for (int i = 0; i < 32; i += 8)
    out[(size_t)(bx + ty + i) * R + by + tx] = f2bf(tile[tx][ty + i]);
}

// Aq = gq*P, Ak = gk*P, Av = gv*Pv ; P/Pv live interleaved in Pcat[4096][1024]
__global__ void gate_kernel(const float* __restrict__ gq, const float* __restrict__ gk,
                            const float* __restrict__ gv, const u16* __restrict__ Pcat,
                            u16* __restrict__ Aq, u16* __restrict__ Ak, u16* __restrict__ Av,
                            int n) {
  int i = (blockIdx.x * blockDim.x + threadIdx.x) * 4;
  if (i >= n) return;
  int s = i >> 9;
  int r = i & 511;
  u16x4 pq = *(const u16x4*)(Pcat + (size_t)s * 1024 + r);
  u16x4 pv = *(const u16x4*)(Pcat + (size_t)s * 1024 + 512 + r);
  f32x4 q = *(const f32x4*)(gq + i);
  f32x4 k = *(const f32x4*)(gk + i);
  f32x4 v = *(const f32x4*)(gv + i);
  u16x4 aq, ak, av;
#pragma unroll
  for (int j = 0; j < 4; ++j) {
    float pf = bf2f(pq[j]);
    float vf = bf2f(pv[j]);
    aq[j] = f2bf(q[j] * pf);
    ak[j] = f2bf(k[j] * pf);
    av[j] = f2bf(v[j] * vf);
  }
  *(u16x4*)(Aq + i) = aq;
  *(u16x4*)(Ak + i) = ak;
  *(u16x4*)(Av + i) = av;
}

// ---------------- generic C = A * Bt^T GEMM ----------------
// A[M][K] bf16 row-major, Bt[N][K] bf16 row-major, C[M][N] (bf16 or f32*scale)
template <bool F32OUT>
__global__ void gemm_bt(const u16* __restrict__ A, const u16* __restrict__ Bt,
                        void* __restrict__ Cp, int M, int N, int K, float scale) {
  __shared__ u16 Al[128 * 32];
  __shared__ u16 Bl[128 * 32];
  const int tid = threadIdx.x;
  const int lane = tid & 63;
  const int w = tid >> 6;
  const int wr = (w >> 1) * 64;
  const int wc = (w & 1) * 64;
  const size_t bm = (size_t)blockIdx.y * 128;
  const size_t bn = (size_t)blockIdx.x * 128;

  f32x4 acc[4][4] = {};

  const int srow = lane >> 2;
  const int sch = lane & 3;
  const int kc = lane >> 4;
  const int rl = lane & 15;

  for (int kt = 0; kt < K; kt += 32) {
#pragma unroll
    for (int half = 0; half < 2; ++half) {
      int rb = half * 64 + w * 16;
      int row = rb + srow;
      int ch = sch ^ ((row >> 1) & 3);
      gload_lds16(A + (bm + row) * (size_t)K + kt + ch * 8, &Al[rb * 32]);
    }
#pragma unroll
    for (int half = 0; half < 2; ++half) {
      int rb = half * 64 + w * 16;
      int row = rb + srow;
      int ch = sch ^ ((row >> 1) & 3);
      gload_lds16(Bt + (bn + row) * (size_t)K + kt + ch * 8, &Bl[rb * 32]);
    }
    asm volatile("s_waitcnt vmcnt(0)" ::: "memory");
    __syncthreads();

    bf16x8 af[4], bfr[4];
#pragma unroll
    for (int m = 0; m < 4; ++m) {
      int row = wr + m * 16 + rl;
      af[m] = ldfrag(&Al[row * 32 + (kc ^ ((row >> 1) & 3)) * 8]);
    }
#pragma unroll
    for (int n = 0; n < 4; ++n) {
      int row = wc + n * 16 + rl;
      bfr[n] = ldfrag(&Bl[row * 32 + (kc ^ ((row >> 1) & 3)) * 8]);
    }
#pragma unroll
    for (int m = 0; m < 4; ++m)
#pragma unroll
      for (int n = 0; n < 4; ++n)
        acc[m][n] = MFMA16(af[m], bfr[n], acc[m][n]);
    __syncthreads();
  }

  const int r0 = (lane >> 4) * 4;
#pragma unroll
  for (int m = 0; m < 4; ++m) {
    size_t grow = bm + wr + m * 16 + r0;
#pragma unroll
    for (int n = 0; n < 4; ++n) {
      size_t gcol = bn + wc + n * 16 + rl;
#pragma unroll
      for (int r = 0; r < 4; ++r) {
        float v = acc[m][n][r] * scale;
        if constexpr (F32OUT)
          ((float*)Cp)[(grow + r) * (size_t)N + gcol] = v;
        else
          ((u16*)Cp)[(grow + r) * (size_t)N + gcol] = f2bf(v);
      }
    }
  }
}

// ---------------- flash attention (causal, 16 heads, d_head=128) ----------------
// grid: x = bh (32) -> linear id % 8 = bh % 8: blocks sharing a head's K/V land
// on one XCD (T1); y = q-tile, qb = 31-y (heavy first, dynamic balancing).
// 1024 blocks; LDS 48KB -> 3 blocks/CU resident (supply was the R4 limiter).
// 4 waves x 16 q-rows. K dbuf 32K + V single 16K; P aliased into Kl[cur].
// V staged per-tile w/ counted vmcnt(4); K prefetch stays in flight across
// the raw mid s_barrier.
__global__ __launch_bounds__(256, 3) void attn_kernel(const u16* __restrict__ Q,
                                                      const u16* __restrict__ Kg,
                                                      const u16* __restrict__ Vt,
                                                      u16* __restrict__ AO) {
  __shared__ u16 Kl[2][64 * 128];  // 32 KB; P (4KB/wave) aliases into Kl[cur]
  __shared__ u16 Vl[128 * 64];     // 16 KB

  const int tid = threadIdx.x;
  const int lane = tid & 63;
  const int w = tid >> 6;
  const int bh = blockIdx.x;
  const int qb = 31 - blockIdx.y;  // heavy q-tiles dispatched first
  const int b = bh >> 4;
  const int h = bh & 15;

  const int rl = lane & 15;
  const int g4 = lane >> 4;

  const float SC = 0.1275255128608411f;  // 1/sqrt(128) * log2(e)
  const float THR = 10.0f;               // defer-rescale threshold (log2 units)

  bf16x8 ones;
  {
    u16x8 ou;
#pragma unroll
    for (int j = 0; j < 8; ++j) ou[j] = 0x3F80;  // bf16 1.0
    ones = __builtin_bit_cast(bf16x8, ou);
  }

  auto stageK = [&](int buf, int t0) {
    int roff = lane >> 4;
    int cch = lane & 15;
#pragma unroll
    for (int i = 0; i < 4; ++i) {
      int rb = w * 16 + i * 4;
      int row = rb + roff;
      int ch = cch ^ (row & 7);
      gload_lds16(Kg + ((size_t)b * 2048 + t0 + row) * 2048 + h * 128 + ch * 8,
                  &Kl[buf][rb * 128]);
    }
  };
  auto stageV = [&](int t0) {
    int roff = lane >> 3;
    int cch = lane & 7;
#pragma unroll
    for (int i = 0; i < 4; ++i) {
      int rb = w * 32 + i * 8;
      int row = rb + roff;
      int ch = cch ^ (row & 7);
      gload_lds16(Vt + (size_t)(h * 128 + row) * 4096 + (size_t)b * 2048 + t0 + ch * 8,
                  &Vl[rb * 64]);
    }
  };

  const int ntiles = qb + 1;
  const int qbase = qb * 64 + w * 16;  // wave's first q row (within b)
  const size_t qrow0 = (size_t)b * 2048 + (size_t)qb * 64;

  bf16x8 qf[4];
  {
    const u16* qp = Q + (qrow0 + w * 16 + rl) * 2048 + h * 128 + g4 * 8;
#pragma unroll
    for (int ks = 0; ks < 4; ++ks) qf[ks] = ldfrag(qp + ks * 32);
  }

  float m_r[4], l_r[4];
#pragma unroll
  for (int r = 0; r < 4; ++r) { m_r[r] = -3.0e38f; l_r[r] = 0.f; }
  f32x4 oacc[8] = {};

  stageK(0, 0);
  __syncthreads();
  int cur = 0;

#pragma unroll 1
  for (int t = 0; t < ntiles; ++t) {
    const int t0 = t * 64;
    stageV(t0);  // V for THIS tile (issued first; drained by vmcnt(4) below)
    const bool pref = (t + 1 < ntiles);
    if (pref) stageK(cur ^ 1, (t + 1) * 64);

    // ---- QK^T ----
    float p[4][4];
    float pmax[4] = {-3.0e38f, -3.0e38f, -3.0e38f, -3.0e38f};
    __builtin_amdgcn_s_setprio(1);
#pragma unroll
    for (int nf = 0; nf < 4; ++nf) {
      f32x4 c = {};
      int trow = nf * 16 + rl;
#pragma unroll
      for (int ks = 0; ks < 4; ++ks) {
        bf16x8 kf = ldfrag(&Kl[cur][trow * 128 + ((ks * 4 + g4) ^ (trow & 7)) * 8]);
        c = MFMA16(qf[ks], kf, c);
      }
      if (t == qb) {  // diagonal tile: causal mask
        int tc = t0 + nf * 16 + rl;
        int fragq = qbase + g4 * 4;  // + r
#pragma unroll
        for (int r = 0; r < 4; ++r)
          p[nf][r] = (tc <= fragq + r) ? c[r] * SC : -3.0e38f;
      } else {
#pragma unroll
        for (int r = 0; r < 4; ++r) p[nf][r] = c[r] * SC;
      }
#pragma unroll
      for (int r = 0; r < 4; ++r) pmax[r] = fmaxf(pmax[r], p[nf][r]);
    }
    __builtin_amdgcn_s_setprio(0);

    // row-max across the 16 t-columns held by rl lanes (register-only)
#pragma unroll
    for (int off = 1; off < 16; off <<= 1)
#pragma unroll
      for (int r = 0; r < 4; ++r)
        pmax[r] = fmaxf(pmax[r], __shfl_xor(pmax[r], off, 16));

    // T13 defer-rescale
    float mg = -3.0e38f;
#pragma unroll
    for (int r = 0; r < 4; ++r) mg = fmaxf(mg, pmax[r] - m_r[r]);
    if (__any(mg > THR)) {
#pragma unroll
      for (int r = 0; r < 4; ++r) {
        float mn = fmaxf(m_r[r], pmax[r]);
        float alpha = exp2f(m_r[r] - mn);
        m_r[r] = mn;
        l_r[r] *= alpha;
#pragma unroll
        for (int nf = 0; nf < 8; ++nf) oacc[nf][r] *= alpha;
      }
    }

    // exp + truncating bf16 pack (register-only, before barrier -> overlaps wait)
    u16 ebf[4][4];
#pragma unroll
    for (int nf = 0; nf < 4; ++nf)
#pragma unroll
      for (int r = 0; r < 4; ++r)
        ebf[nf][r] = f2bf_trunc(exp2f(p[nf][r] - m_r[r]));

    // Drain own V loads (K prefetch stays in flight), then join waves:
    // after this barrier all QK reads of Kl[cur] are register-consumed and
    // all waves' V staging is complete.
    if (pref) asm volatile("s_waitcnt vmcnt(4)\n\ts_barrier" ::: "memory");
    else      asm volatile("s_waitcnt vmcnt(0)\n\ts_barrier" ::: "memory");

    // P -> LDS (bf16, swizzled), aliased into Kl[cur] (dead after QK^T)
    u16* pl = &Kl[cur][w * 1024];
#pragma unroll
    for (int nf = 0; nf < 4; ++nf) {
      int tt = nf * 16 + rl;
#pragma unroll
      for (int r = 0; r < 4; ++r) {
        int q = g4 * 4 + r;
        pl[q * 64 + ((tt >> 3) ^ (q & 7)) * 8 + (tt & 7)] = ebf[nf][r];
      }
    }

    // ---- PV (+ rsum via MFMA with ones) ----
    __builtin_amdgcn_s_setprio(1);
    f32x4 rs = {};
#pragma unroll
    for (int ks = 0; ks < 2; ++ks) {
      bf16x8 pa = ldfrag(&pl[rl * 64 + ((ks * 4 + g4) ^ (rl & 7)) * 8]);
#pragma unroll
      for (int nf = 0; nf < 8; ++nf) {
        int drow = nf * 16 + rl;
        bf16x8 vf = ldfrag(&Vl[drow * 64 + ((ks * 4 + g4) ^ (drow & 7)) * 8]);
        oacc[nf] = MFMA16(pa, vf, oacc[nf]);
      }
      rs = MFMA16(pa, ones, rs);
    }
    __builtin_amdgcn_s_setprio(0);
#pragma unroll
    for (int r = 0; r < 4; ++r) l_r[r] += rs[r];

    __syncthreads();  // all waves done with Vl/pl; drains K prefetch
    cur ^= 1;
  }

  // epilogue
#pragma unroll
  for (int nf = 0; nf < 8; ++nf) {
    size_t dc = (size_t)h * 128 + nf * 16 + rl;
#pragma unroll
    for (int r = 0; r < 4; ++r) {
      float v = oacc[nf][r] / l_r[r];
      AO[(qrow0 + w * 16 + g4 * 4 + r) * 2048 + dc] = f2bf(v);
    }
  }
}

// ---------------- launch ----------------

extern "C" void kernel_launch(void* const* d_in, const int* in_sizes, int n_in,
                              void* d_out, int out_size, void* d_ws, size_t ws_size,
                              hipStream_t stream) {
  const float* x = (const float*)d_in[0];
  const float* gQ = (const float*)d_in[1];
  const float* gK = (const float*)d_in[2];
  const float* gV = (const float*)d_in[3];
  const float* qkr = (const float*)d_in[4];
  const float* qkw = (const float*)d_in[5];
  const float* vr = (const float*)d_in[6];
  const float* vw = (const float*)d_in[7];
  const float* wo = (const float*)d_in[8];
  float* out = (float*)d_out;

  u16* p = (u16*)d_ws;
  u16* x_bf = p;   p += 8388608;   // [4096][2048]; later reused as Vt [2048][4096]
  u16* qkr_b = p;  p += 1048576;   // [512][2048]  \ adjacent -> Bt_cat [1024][2048]
  u16* vr_b = p;   p += 1048576;   // [512][2048]  /
  u16* qkwT = p;   p += 1048576;   // [2048][512]
  u16* vwT = p;    p += 1048576;   // [2048][512]
  u16* woT = p;    p += 4194304;   // [2048][2048]
  u16* Pcat = p;   p += 4194304;   // [4096][1024] (P | Pv)
  u16* Aq = p;     p += 2097152;   // [4096][512]  \ adjacent -> A_cat [8192][512]
  u16* Ak = p;     p += 2097152;   // [4096][512]  /
  u16* Av = p;     p += 2097152;   // [4096][512]
  u16* Qb = p;     p += 8388608;   // [4096][2048] \ adjacent -> C_cat [8192][2048]
  u16* Kb = p;     p += 8388608;   // [4096][2048] /
  u16* Vt = x_bf;                  // alias: x_bf dead after Pcat GEMM
  u16* AO = Qb;                    // alias: block writes exactly the Q region it read

  cvt_kernel<<<8192, 256, 0, stream>>>(x, x_bf, 8388608);
  cvt_kernel<<<1024, 256, 0, stream>>>(qkr, qkr_b, 1048576);
  cvt_kernel<<<1024, 256, 0, stream>>>(vr, vr_b, 1048576);
  tcvt_kernel<<<dim3(64, 16), dim3(32, 8), 0, stream>>>(qkw, qkwT, 512, 2048);
  tcvt_kernel<<<dim3(64, 16), dim3(32, 8), 0, stream>>>(vw, vwT, 512, 2048);
  tcvt_kernel<<<dim3(64, 64), dim3(32, 8), 0, stream>>>(wo, woT, 2048, 2048);

  // Pcat = x_bf * [qk_read;v_read]^T   (M=4096, N=1024, K=2048)
  gemm_bt<false><<<dim3(8, 32), 256, 0, stream>>>(x_bf, qkr_b, Pcat, 4096, 1024, 2048, 1.f);

  gate_kernel<<<2048, 256, 0, stream>>>(gQ, gK, gV, Pcat, Aq, Ak, Av, 2097152);

  // [Q;K] = [Aq;Ak] * qk_write   (M=8192, N=2048, K=512)
  gemm_bt<false><<<dim3(16, 64), 256, 0, stream>>>(Aq, qkwT, Qb, 8192, 2048, 512, 1.f);

  // Vt = vwT * Av^T   (M=2048, N=4096, K=512)
  gemm_bt<false><<<dim3(32, 16), 256, 0, stream>>>(vwT, Av, Vt, 2048, 4096, 512, 1.f);

  // attention -> AO (bf16, [4096][2048])
  attn_kernel<<<dim3(32, 32), 256, 0, stream>>>(Qb, Kb, Vt, AO);

  // out = AO * W_O * 1/keep^2   (f32 out)
  gemm_bt<true><<<dim3(16, 32), 256, 0, stream>>>(AO, woT, out, 4096, 2048, 2048,
                                                  1.2345679012345678f);
}

// Round 6
// 227.216 us; speedup vs baseline: 1.1493x; 1.0898x over previous
//
#include <hip/hip_runtime.h>
#include <cstdint>
#include <cstddef>

typedef unsigned short u16;
typedef unsigned int u32;
typedef __attribute__((ext_vector_type(4))) float f32x4;
typedef __attribute__((ext_vector_type(8))) __bf16 bf16x8;
typedef __attribute__((ext_vector_type(8))) u16 u16x8;
typedef __attribute__((ext_vector_type(4))) u16 u16x4;
typedef __attribute__((ext_vector_type(2))) u32 u32x2;

__device__ __forceinline__ u16 f2bf(float x) {
  u32 u = __builtin_bit_cast(u32, x);
  u += 0x7fffu + ((u >> 16) & 1u);
  return (u16)(u >> 16);
}
__device__ __forceinline__ float bf2f(u16 b) {
  return __builtin_bit_cast(float, (u32)b << 16);
}
__device__ __forceinline__ bf16x8 ldfrag(const u16* p) {
  return __builtin_bit_cast(bf16x8, *(const u16x8*)p);
}
__device__ __forceinline__ void gload_lds16(const void* g, void* l) {
  auto gp = (const __attribute__((address_space(1))) u32*)g;
  auto lp = (__attribute__((address_space(3))) u32*)l;
  __builtin_amdgcn_global_load_lds(gp, lp, 16, 0, 0);
}
#define MFMA16(a, b, c) __builtin_amdgcn_mfma_f32_16x16x32_bf16(a, b, c, 0, 0, 0)

// ---------------- elementwise converts ----------------

__global__ void cvt_kernel(const float* __restrict__ in, u16* __restrict__ out, int n) {
  int i = (blockIdx.x * blockDim.x + threadIdx.x) * 4;
  if (i >= n) return;
  f32x4 v = *(const f32x4*)(in + i);
  u16x4 r = { f2bf(v[0]), f2bf(v[1]), f2bf(v[2]), f2bf(v[3]) };
  *(u16x4*)(out + i) = r;
}

// out[C][R] = bf16(in[R][C]^T), tiled transpose via LDS
__global__ void tcvt_kernel(const float* __restrict__ in, u16* __restrict__ out, int R, int C) {
  __shared__ float tile[32][33];
  int bx = blockIdx.x * 32, by = blockIdx.y * 32;
  int tx = threadIdx.x, ty = threadIdx.y;
#pragma unroll
  for (int i = 0; i < 32; i += 8)
    tile[ty + i][tx] = in[(size_t)(by + ty + i) * C + bx + tx];
  __syncthreads();
#pragma unroll
  for (int i = 0; i < 32; i += 8)
    out[(size_t)(bx + ty + i) * R + by + tx] = f2bf(tile[tx][ty + i]);
}

// Aq = gq*P*SC (attention scale+log2e pre-folded into Q), Ak = gk*P, Av = gv*Pv
__global__ void gate_kernel(const float* __restrict__ gq, const float* __restrict__ gk,
                            const float* __restrict__ gv, const u16* __restrict__ Pcat,
                            u16* __restrict__ Aq, u16* __restrict__ Ak, u16* __restrict__ Av,
                            int n) {
  const float SC = 0.1275255128608411f;  // 1/sqrt(128) * log2(e)
  int i = (blockIdx.x * blockDim.x + threadIdx.x) * 4;
  if (i >= n) return;
  int s = i >> 9;
  int r = i & 511;
  u16x4 pq = *(const u16x4*)(Pcat + (size_t)s * 1024 + r);
  u16x4 pv = *(const u16x4*)(Pcat + (size_t)s * 1024 + 512 + r);
  f32x4 q = *(const f32x4*)(gq + i);
  f32x4 k = *(const f32x4*)(gk + i);
  f32x4 v = *(const f32x4*)(gv + i);
  u16x4 aq, ak, av;
#pragma unroll
  for (int j = 0; j < 4; ++j) {
    float pf = bf2f(pq[j]);
    float vf = bf2f(pv[j]);
    aq[j] = f2bf(q[j] * SC * pf);
    ak[j] = f2bf(k[j] * pf);
    av[j] = f2bf(v[j] * vf);
  }
  *(u16x4*)(Aq + i) = aq;
  *(u16x4*)(Ak + i) = ak;
  *(u16x4*)(Av + i) = av;
}

// ---------------- generic C = A * Bt^T GEMM ----------------
// A[M][K] bf16 row-major, Bt[N][K] bf16 row-major, C[M][N] (bf16 or f32*scale)
template <bool F32OUT>
__global__ void gemm_bt(const u16* __restrict__ A, const u16* __restrict__ Bt,
                        void* __restrict__ Cp, int M, int N, int K, float scale) {
  __shared__ u16 Al[128 * 32];
  __shared__ u16 Bl[128 * 32];
  const int tid = threadIdx.x;
  const int lane = tid & 63;
  const int w = tid >> 6;
  const int wr = (w >> 1) * 64;
  const int wc = (w & 1) * 64;
  const size_t bm = (size_t)blockIdx.y * 128;
  const size_t bn = (size_t)blockIdx.x * 128;

  f32x4 acc[4][4] = {};

  const int srow = lane >> 2;
  const int sch = lane & 3;
  const int kc = lane >> 4;
  const int rl = lane & 15;

  for (int kt = 0; kt < K; kt += 32) {
#pragma unroll
    for (int half = 0; half < 2; ++half) {
      int rb = half * 64 + w * 16;
      int row = rb + srow;
      int ch = sch ^ ((row >> 1) & 3);
      gload_lds16(A + (bm + row) * (size_t)K + kt + ch * 8, &Al[rb * 32]);
    }
#pragma unroll
    for (int half = 0; half < 2; ++half) {
      int rb = half * 64 + w * 16;
      int row = rb + srow;
      int ch = sch ^ ((row >> 1) & 3);
      gload_lds16(Bt + (bn + row) * (size_t)K + kt + ch * 8, &Bl[rb * 32]);
    }
    asm volatile("s_waitcnt vmcnt(0)" ::: "memory");
    __syncthreads();

    bf16x8 af[4], bfr[4];
#pragma unroll
    for (int m = 0; m < 4; ++m) {
      int row = wr + m * 16 + rl;
      af[m] = ldfrag(&Al[row * 32 + (kc ^ ((row >> 1) & 3)) * 8]);
    }
#pragma unroll
    for (int n = 0; n < 4; ++n) {
      int row = wc + n * 16 + rl;
      bfr[n] = ldfrag(&Bl[row * 32 + (kc ^ ((row >> 1) & 3)) * 8]);
    }
#pragma unroll
    for (int m = 0; m < 4; ++m)
#pragma unroll
      for (int n = 0; n < 4; ++n)
        acc[m][n] = MFMA16(af[m], bfr[n], acc[m][n]);
    __syncthreads();
  }

  const int r0 = (lane >> 4) * 4;
#pragma unroll
  for (int m = 0; m < 4; ++m) {
    size_t grow = bm + wr + m * 16 + r0;
#pragma unroll
    for (int n = 0; n < 4; ++n) {
      size_t gcol = bn + wc + n * 16 + rl;
#pragma unroll
      for (int r = 0; r < 4; ++r) {
        float v = acc[m][n][r] * scale;
        if constexpr (F32OUT)
          ((float*)Cp)[(grow + r) * (size_t)N + gcol] = v;
        else
          ((u16*)Cp)[(grow + r) * (size_t)N + gcol] = f2bf(v);
      }
    }
  }
}

// ---------------- flash attention (causal, 16 heads, d_head=128) ----------------
// grid: x = bh (32) -> T1 XCD locality; y = q-tile, qb = 31-y (heavy first).
// 4 waves x 16 q-rows. K dbuf 32K + V single 16K; P aliased into Kl[cur].
// SWAPPED QK^T (T12): c = mfma(K, Q) -> P[t][q], q = lane&15 -> in-register
// softmax: scalar m per lane, 2-shfl row max, b64-packed P stores. Q comes
// pre-scaled by 1/sqrt(128)*log2(e) from gate_kernel.
__global__ __launch_bounds__(256, 3) void attn_kernel(const u16* __restrict__ Q,
                                                      const u16* __restrict__ Kg,
                                                      const u16* __restrict__ Vt,
                                                      u16* __restrict__ AO) {
  __shared__ u16 Kl[2][64 * 128];  // 32 KB; P (2KB/wave) aliases into Kl[cur]
  __shared__ u16 Vl[128 * 64];     // 16 KB

  const int tid = threadIdx.x;
  const int lane = tid & 63;
  const int w = tid >> 6;
  const int bh = blockIdx.x;
  const int qb = 31 - blockIdx.y;  // heavy q-tiles dispatched first
  const int b = bh >> 4;
  const int h = bh & 15;

  const int rl = lane & 15;
  const int g4 = lane >> 4;

  const float THR = 10.0f;  // defer-rescale threshold (log2 units)

  bf16x8 ones;
  {
    u16x8 ou;
#pragma unroll
    for (int j = 0; j < 8; ++j) ou[j] = 0x3F80;  // bf16 1.0
    ones = __builtin_bit_cast(bf16x8, ou);
  }

  auto stageK = [&](int buf, int t0) {
    int roff = lane >> 4;
    int cch = lane & 15;
#pragma unroll
    for (int i = 0; i < 4; ++i) {
      int rb = w * 16 + i * 4;
      int row = rb + roff;
      int ch = cch ^ (row & 7);
      gload_lds16(Kg + ((size_t)b * 2048 + t0 + row) * 2048 + h * 128 + ch * 8,
                  &Kl[buf][rb * 128]);
    }
  };
  auto stageV = [&](int t0) {
    int roff = lane >> 3;
    int cch = lane & 7;
#pragma unroll
    for (int i = 0; i < 4; ++i) {
      int rb = w * 32 + i * 8;
      int row = rb + roff;
      int ch = cch ^ (row & 7);
      gload_lds16(Vt + (size_t)(h * 128 + row) * 4096 + (size_t)b * 2048 + t0 + ch * 8,
                  &Vl[rb * 64]);
    }
  };

  const int ntiles = qb + 1;
  const int qq = qb * 64 + w * 16 + rl;  // this lane's q row (within b)
  const size_t qrow0 = (size_t)b * 2048 + (size_t)qb * 64;

  bf16x8 qf[4];
  {
    const u16* qp = Q + (qrow0 + w * 16 + rl) * 2048 + h * 128 + g4 * 8;
#pragma unroll
    for (int ks = 0; ks < 4; ++ks) qf[ks] = ldfrag(qp + ks * 32);
  }

  float m_r = -3.0e38f;  // running max for q row = qq (per lane)
  float l_r[4];          // denominator in MFMA-row layout (rows g4*4+r)
#pragma unroll
  for (int r = 0; r < 4; ++r) l_r[r] = 0.f;
  f32x4 oacc[8] = {};

  stageK(0, 0);
  __syncthreads();
  int cur = 0;

#pragma unroll 1
  for (int t = 0; t < ntiles; ++t) {
    const int t0 = t * 64;
    stageV(t0);  // V for THIS tile (issued first; drained by vmcnt(4) below)
    const bool pref = (t + 1 < ntiles);
    if (pref) stageK(cur ^ 1, (t + 1) * 64);

    // ---- QK^T, swapped: c = mfma(K, Q) -> P[t = nf*16+g4*4+r][q = rl] ----
    float p[4][4];
    __builtin_amdgcn_s_setprio(1);
#pragma unroll
    for (int nf = 0; nf < 4; ++nf) {
      f32x4 c = {};
      int trow = nf * 16 + rl;
#pragma unroll
      for (int ks = 0; ks < 4; ++ks) {
        bf16x8 kf = ldfrag(&Kl[cur][trow * 128 + ((ks * 4 + g4) ^ (trow & 7)) * 8]);
        c = MFMA16(kf, qf[ks], c);
      }
      if (t == qb) {  // diagonal tile: causal mask (t_global <= qq)
        int tb = t0 + nf * 16 + g4 * 4;
#pragma unroll
        for (int r = 0; r < 4; ++r)
          p[nf][r] = (tb + r <= qq) ? c[r] : -3.0e38f;
      } else {
#pragma unroll
        for (int r = 0; r < 4; ++r) p[nf][r] = c[r];
      }
    }
    __builtin_amdgcn_s_setprio(0);

    // row max: 15 in-lane fmax + 2 shfl_xor across g4 groups
    float mx = p[0][0];
#pragma unroll
    for (int nf = 0; nf < 4; ++nf)
#pragma unroll
      for (int r = 0; r < 4; ++r) mx = fmaxf(mx, p[nf][r]);
    mx = fmaxf(mx, __shfl_xor(mx, 16));
    mx = fmaxf(mx, __shfl_xor(mx, 32));

    // T13 defer-rescale (scalar m per lane; alpha pulled to row layout on trigger)
    if (__any(mx - m_r > THR)) {
      float mn = fmaxf(m_r, mx);
      float alpha = exp2f(m_r - mn);
      m_r = mn;
#pragma unroll
      for (int r = 0; r < 4; ++r) {
        float av = __shfl(alpha, g4 * 4 + r, 16);
        l_r[r] *= av;
#pragma unroll
        for (int nf = 0; nf < 8; ++nf) oacc[nf][r] *= av;
      }
    }

    // exp + pack pairs (trunc) -> 2 u32 per nf (register-only, before barrier)
    u32x2 pk[4];
#pragma unroll
    for (int nf = 0; nf < 4; ++nf) {
      u32 e0 = __builtin_bit_cast(u32, exp2f(p[nf][0] - m_r));
      u32 e1 = __builtin_bit_cast(u32, exp2f(p[nf][1] - m_r));
      u32 e2 = __builtin_bit_cast(u32, exp2f(p[nf][2] - m_r));
      u32 e3 = __builtin_bit_cast(u32, exp2f(p[nf][3] - m_r));
      pk[nf][0] = (e1 & 0xffff0000u) | (e0 >> 16);
      pk[nf][1] = (e3 & 0xffff0000u) | (e2 >> 16);
    }

    // Drain own V loads (K prefetch stays in flight), then join waves:
    // all QK reads of Kl[cur] are register-consumed before this barrier.
    if (pref) asm volatile("s_waitcnt vmcnt(4)\n\ts_barrier" ::: "memory");
    else      asm volatile("s_waitcnt vmcnt(0)\n\ts_barrier" ::: "memory");

    // P -> LDS: 4 x ds_write_b64, swizzled; aliased into Kl[cur] (dead tile)
    // layout: pl[q=rl][t], chunk (t>>3) = nf*2+(g4>>1) XOR'd with (rl&7)
    u16* pl = &Kl[cur][w * 1024];
#pragma unroll
    for (int nf = 0; nf < 4; ++nf) {
      int c8 = ((nf * 2 + (g4 >> 1)) ^ (rl & 7)) * 8 + (g4 & 1) * 4;
      *(u32x2*)(&pl[rl * 64 + c8]) = pk[nf];
    }

    // ---- PV (+ rsum via MFMA with ones) ----
    __builtin_amdgcn_s_setprio(1);
    f32x4 rs = {};
#pragma unroll
    for (int ks = 0; ks < 2; ++ks) {
      bf16x8 pa = ldfrag(&pl[rl * 64 + ((ks * 4 + g4) ^ (rl & 7)) * 8]);
#pragma unroll
      for (int nf = 0; nf < 8; ++nf) {
        int drow = nf * 16 + rl;
        bf16x8 vf = ldfrag(&Vl[drow * 64 + ((ks * 4 + g4) ^ (drow & 7)) * 8]);
        oacc[nf] = MFMA16(pa, vf, oacc[nf]);
      }
      rs = MFMA16(pa, ones, rs);
    }
    __builtin_amdgcn_s_setprio(0);
#pragma unroll
    for (int r = 0; r < 4; ++r) l_r[r] += rs[r];

    __syncthreads();  // all waves done with Vl/pl; drains K prefetch
    cur ^= 1;
  }

  // epilogue (oacc and l_r share the MFMA-row layout)
#pragma unroll
  for (int nf = 0; nf < 8; ++nf) {
    size_t dc = (size_t)h * 128 + nf * 16 + rl;
#pragma unroll
    for (int r = 0; r < 4; ++r) {
      float v = oacc[nf][r] / l_r[r];
      AO[(qrow0 + w * 16 + g4 * 4 + r) * 2048 + dc] = f2bf(v);
    }
  }
}

// ---------------- launch ----------------

extern "C" void kernel_launch(void* const* d_in, const int* in_sizes, int n_in,
                              void* d_out, int out_size, void* d_ws, size_t ws_size,
                              hipStream_t stream) {
  const float* x = (const float*)d_in[0];
  const float* gQ = (const float*)d_in[1];
  const float* gK = (const float*)d_in[2];
  const float* gV = (const float*)d_in[3];
  const float* qkr = (const float*)d_in[4];
  const float* qkw = (const float*)d_in[5];
  const float* vr = (const float*)d_in[6];
  const float* vw = (const float*)d_in[7];
  const float* wo = (const float*)d_in[8];
  float* out = (float*)d_out;

  u16* p = (u16*)d_ws;
  u16* x_bf = p;   p += 8388608;   // [4096][2048]; later reused as Vt [2048][4096]
  u16* qkr_b = p;  p += 1048576;   // [512][2048]  \ adjacent -> Bt_cat [1024][2048]
  u16* vr_b = p;   p += 1048576;   // [512][2048]  /
  u16* qkwT = p;   p += 1048576;   // [2048][512]
  u16* vwT = p;    p += 1048576;   // [2048][512]
  u16* woT = p;    p += 4194304;   // [2048][2048]
  u16* Pcat = p;   p += 4194304;   // [4096][1024] (P | Pv)
  u16* Aq = p;     p += 2097152;   // [4096][512]  \ adjacent -> A_cat [8192][512]
  u16* Ak = p;     p += 2097152;   // [4096][512]  /
  u16* Av = p;     p += 2097152;   // [4096][512]
  u16* Qb = p;     p += 8388608;   // [4096][2048] \ adjacent -> C_cat [8192][2048]
  u16* Kb = p;     p += 8388608;   // [4096][2048] /
  u16* Vt = x_bf;                  // alias: x_bf dead after Pcat GEMM
  u16* AO = Qb;                    // alias: block writes exactly the Q region it read

  cvt_kernel<<<8192, 256, 0, stream>>>(x, x_bf, 8388608);
  cvt_kernel<<<1024, 256, 0, stream>>>(qkr, qkr_b, 1048576);
  cvt_kernel<<<1024, 256, 0, stream>>>(vr, vr_b, 1048576);
  tcvt_kernel<<<dim3(64, 16), dim3(32, 8), 0, stream>>>(qkw, qkwT, 512, 2048);
  tcvt_kernel<<<dim3(64, 16), dim3(32, 8), 0, stream>>>(vw, vwT, 512, 2048);
  tcvt_kernel<<<dim3(64, 64), dim3(32, 8), 0, stream>>>(wo, woT, 2048, 2048);

  // Pcat = x_bf * [qk_read;v_read]^T   (M=4096, N=1024, K=2048)
  gemm_bt<false><<<dim3(8, 32), 256, 0, stream>>>(x_bf, qkr_b, Pcat, 4096, 1024, 2048, 1.f);

  gate_kernel<<<2048, 256, 0, stream>>>(gQ, gK, gV, Pcat, Aq, Ak, Av, 2097152);

  // [Q;K] = [Aq;Ak] * qk_write   (M=8192, N=2048, K=512); Q pre-scaled via gate
  gemm_bt<false><<<dim3(16, 64), 256, 0, stream>>>(Aq, qkwT, Qb, 8192, 2048, 512, 1.f);

  // Vt = vwT * Av^T   (M=2048, N=4096, K=512)
  gemm_bt<false><<<dim3(32, 16), 256, 0, stream>>>(vwT, Av, Vt, 2048, 4096, 512, 1.f);

  // attention -> AO (bf16, [4096][2048])
  attn_kernel<<<dim3(32, 32), 256, 0, stream>>>(Qb, Kb, Vt, AO);

  // out = AO * W_O * 1/keep^2   (f32 out)
  gemm_bt<true><<<dim3(16, 32), 256, 0, stream>>>(AO, woT, out, 4096, 2048, 2048,
                                                  1.2345679012345678f);
}